// Round 4
// baseline (898.571 us; speedup 1.0000x reference)
//
#include <hip/hip_runtime.h>

#define T_LEN 512
#define HID 50
#define NBATCH 4096
#define BPW 2        // batches per wave
#define WAVES 4      // waves per block
#define CHUNK 64     // timesteps per x-prefetch chunk

__device__ __forceinline__ float rl(float v, int l) {
  return __int_as_float(__builtin_amdgcn_readlane(__float_as_int(v), l));
}
__device__ __forceinline__ float sigm(float v) {
  return __builtin_amdgcn_rcpf(1.0f + __builtin_amdgcn_exp2f(-1.442695041f * v));
}
__device__ __forceinline__ float tanh_f(float v) {
  return 1.0f - 2.0f * __builtin_amdgcn_rcpf(1.0f + __builtin_amdgcn_exp2f(2.885390082f * v));
}

__global__ __launch_bounds__(256, 2)
void gru_fused_kernel(const float* __restrict__ x,
                      const float* __restrict__ W_ih,
                      const float* __restrict__ W_hh,
                      const float* __restrict__ b_ih,
                      const float* __restrict__ b_hh,
                      const float* __restrict__ W_fc,
                      const float* __restrict__ b_fc,
                      float* __restrict__ out) {
  const int tid  = threadIdx.x;
  const int lane = tid & 63;
  const int wv   = tid >> 6;
  const int b0   = (blockIdx.x * WAVES + wv) * BPW;
  const int ic   = (lane < HID) ? lane : (HID - 1);

  // per-lane input-weight / bias constants
  const float u_r0 = W_ih[ic * 3 + 0],         u_r1 = W_ih[ic * 3 + 1],         u_r2 = W_ih[ic * 3 + 2];
  const float u_z0 = W_ih[(50 + ic) * 3 + 0],  u_z1 = W_ih[(50 + ic) * 3 + 1],  u_z2 = W_ih[(50 + ic) * 3 + 2];
  const float u_n0 = W_ih[(100 + ic) * 3 + 0], u_n1 = W_ih[(100 + ic) * 3 + 1], u_n2 = W_ih[(100 + ic) * 3 + 2];
  const float c_r  = b_ih[ic] + b_hh[ic];
  const float c_z  = b_ih[50 + ic] + b_hh[50 + ic];
  const float c_ni = b_ih[100 + ic];
  const float c_nh = b_hh[100 + ic];

  // ---- lane's W_hh rows -> scalar register arrays, loaded DIRECTLY from global
  // (global loads are never sunk into the loop; rows are 8B-aligned -> float2) ----
  float wr[52], wz[52], wn[52];
  {
    const float2* pr = (const float2*)(W_hh + ic * HID);
    const float2* pz = (const float2*)(W_hh + (50 + ic) * HID);
    const float2* pn = (const float2*)(W_hh + (100 + ic) * HID);
#pragma unroll
    for (int j = 0; j < 25; ++j) {
      float2 a = pr[j]; wr[2 * j] = a.x; wr[2 * j + 1] = a.y;
      float2 b = pz[j]; wz[2 * j] = b.x; wz[2 * j + 1] = b.y;
      float2 c = pn[j]; wn[2 * j] = c.x; wn[2 * j + 1] = c.y;
    }
    wr[50] = wr[51] = 0.0f;
    wz[50] = wz[51] = 0.0f;
    wn[50] = wn[51] = 0.0f;
  }
  // pin weights in VGPRs: opaque to rematerialization/refolding
#pragma unroll
  for (int j = 0; j < 52; ++j) {
    asm volatile("" : "+v"(wr[j]), "+v"(wz[j]), "+v"(wn[j]));
  }

  float h[BPW] = {0.0f, 0.0f};

  float xA[BPW], xB[BPW], xC[BPW];
#pragma unroll
  for (int k = 0; k < BPW; ++k) {
    const float* p = x + (size_t)(b0 + k) * (T_LEN * 3) + lane * 3;
    xA[k] = p[0]; xB[k] = p[1]; xC[k] = p[2];
  }

  for (int tc = 0; tc < T_LEN / CHUNK; ++tc) {
    float nA[BPW], nB[BPW], nC[BPW];
    if (tc + 1 < T_LEN / CHUNK) {
#pragma unroll
      for (int k = 0; k < BPW; ++k) {
        const float* p = x + (size_t)(b0 + k) * (T_LEN * 3) + (tc + 1) * (CHUNK * 3) + lane * 3;
        nA[k] = p[0]; nB[k] = p[1]; nC[k] = p[2];
      }
    }

    for (int s = 0; s < CHUNK; ++s) {
      float ar[BPW] = {0.f, 0.f};
      float az[BPW] = {0.f, 0.f};
      float an[BPW] = {0.f, 0.f};

#pragma unroll
      for (int q = 0; q < 13; ++q) {
#pragma unroll
        for (int k = 0; k < BPW; ++k) {
          const float h0 = rl(h[k], 4 * q + 0);
          const float h1 = rl(h[k], 4 * q + 1);
          const float h2 = rl(h[k], 4 * q + 2);
          const float h3 = rl(h[k], 4 * q + 3);
          ar[k] = fmaf(wr[4 * q + 0], h0, ar[k]); ar[k] = fmaf(wr[4 * q + 1], h1, ar[k]);
          ar[k] = fmaf(wr[4 * q + 2], h2, ar[k]); ar[k] = fmaf(wr[4 * q + 3], h3, ar[k]);
          az[k] = fmaf(wz[4 * q + 0], h0, az[k]); az[k] = fmaf(wz[4 * q + 1], h1, az[k]);
          az[k] = fmaf(wz[4 * q + 2], h2, az[k]); az[k] = fmaf(wz[4 * q + 3], h3, az[k]);
          an[k] = fmaf(wn[4 * q + 0], h0, an[k]); an[k] = fmaf(wn[4 * q + 1], h1, an[k]);
          an[k] = fmaf(wn[4 * q + 2], h2, an[k]); an[k] = fmaf(wn[4 * q + 3], h3, an[k]);
        }
      }

#pragma unroll
      for (int k = 0; k < BPW; ++k) {
        const float x0 = rl(xA[k], s);
        const float x1 = rl(xB[k], s);
        const float x2 = rl(xC[k], s);
        const float gr = fmaf(x0, u_r0, fmaf(x1, u_r1, fmaf(x2, u_r2, c_r)));
        const float gz = fmaf(x0, u_z0, fmaf(x1, u_z1, fmaf(x2, u_z2, c_z)));
        const float gn = fmaf(x0, u_n0, fmaf(x1, u_n1, fmaf(x2, u_n2, c_ni)));
        const float r  = sigm(ar[k] + gr);
        const float z  = sigm(az[k] + gz);
        const float nv = gn + r * (an[k] + c_nh);
        const float n  = tanh_f(nv);
        h[k] = n + z * (h[k] - n);
      }
    }

#pragma unroll
    for (int k = 0; k < BPW; ++k) { xA[k] = nA[k]; xB[k] = nB[k]; xC[k] = nC[k]; }
  }

  const float wfc = (lane < HID) ? W_fc[lane] : 0.0f;
#pragma unroll
  for (int k = 0; k < BPW; ++k) {
    float p = (lane < HID) ? h[k] * wfc : 0.0f;
#pragma unroll
    for (int off = 32; off > 0; off >>= 1) p += __shfl_down(p, off);
    if (lane == 0) out[b0 + k] = p + b_fc[0];
  }
}

extern "C" void kernel_launch(void* const* d_in, const int* in_sizes, int n_in,
                              void* d_out, int out_size, void* d_ws, size_t ws_size,
                              hipStream_t stream) {
  const float* x    = (const float*)d_in[0];
  const float* W_ih = (const float*)d_in[1];
  const float* W_hh = (const float*)d_in[2];
  const float* b_ih = (const float*)d_in[3];
  const float* b_hh = (const float*)d_in[4];
  const float* W_fc = (const float*)d_in[5];
  const float* b_fc = (const float*)d_in[6];
  float* out = (float*)d_out;

  dim3 grid(NBATCH / (WAVES * BPW));   // 512 blocks -> 2 blocks/CU -> 2 waves/SIMD
  dim3 block(256);
  gru_fused_kernel<<<grid, block, 0, stream>>>(x, W_ih, W_hh, b_ih, b_hh, W_fc, b_fc, out);
}

// Round 5
// 299.904 us; speedup vs baseline: 2.9962x; 2.9962x over previous
//
#include <hip/hip_runtime.h>
#include <hip/hip_bf16.h>

#define T_LEN 512
#define HID 50
#define NBATCH 4096

using short8  = __attribute__((ext_vector_type(8))) short;
using floatx4 = __attribute__((ext_vector_type(4))) float;

__device__ __forceinline__ float sigm(float v) {
  return __builtin_amdgcn_rcpf(1.0f + __builtin_amdgcn_exp2f(-1.442695041f * v));
}
__device__ __forceinline__ float tanh_f(float v) {
  return 1.0f - 2.0f * __builtin_amdgcn_rcpf(1.0f + __builtin_amdgcn_exp2f(2.885390082f * v));
}

// A-fragment read: two ds_read_b64 from a bf16 plane laid out [m][u] (row=128B)
// with per-row XOR swizzle ((m&7)<<4). qbase=0 -> k in [0,32), qbase=2 -> [32,64).
__device__ __forceinline__ short8 afrag(const char* plane, int rowoff, int kg, int qbase, int xr) {
  unsigned long long a = *(const unsigned long long*)(plane + rowoff + ((((qbase + 0) * 32) + 8 * kg) ^ xr));
  unsigned long long b = *(const unsigned long long*)(plane + rowoff + ((((qbase + 1) * 32) + 8 * kg) ^ xr));
  union { unsigned long long u[2]; short8 s; } t;
  t.u[0] = a; t.u[1] = b;
  return t.s;
}

__global__ __launch_bounds__(256, 1)
void gru_mfma_kernel(const float* __restrict__ x,
                     const float* __restrict__ W_ih,
                     const float* __restrict__ W_hh,
                     const float* __restrict__ b_ih,
                     const float* __restrict__ b_hh,
                     const float* __restrict__ W_fc,
                     const float* __restrict__ b_fc,
                     float* __restrict__ out) {
  // LDS map (bytes): [0,12288) x-chunk [t64][c3][m16] f32
  //                  [12288,16384) h buf0 (hi plane 2048 + lo plane 2048), bf16 [m16][u64] XOR-swizzled
  //                  [16384,20480) h buf1
  __shared__ alignas(16) unsigned char lds[20480];
  char* xs   = (char*)lds;
  char* hbuf = (char*)lds + 12288;

  const int tid  = threadIdx.x;
  const int lane = tid & 63;
  const int w    = tid >> 6;          // wave id: owns units 16w..16w+15
  const int ucol = lane & 15;         // N-col within tile / A-row batch index
  const int kg   = lane >> 4;         // k-group for A/B frags; m-group for C rows
  const int b0   = blockIdx.x * 16;
  const int u    = 16 * w + ucol;     // this lane's hidden unit
  const bool uv  = (u < HID);

  // ---- per-lane bias / input-weight constants (zero-guarded for pad units) ----
  const float c_r  = uv ? (b_ih[u] + b_hh[u]) : 0.f;
  const float c_z  = uv ? (b_ih[50 + u] + b_hh[50 + u]) : 0.f;
  const float c_ni = uv ? b_ih[100 + u] : 0.f;
  const float c_nh = uv ? b_hh[100 + u] : 0.f;
  float u_r[3], u_z[3], u_n[3];
#pragma unroll
  for (int c = 0; c < 3; ++c) {
    u_r[c] = uv ? W_ih[u * 3 + c] : 0.f;
    u_z[c] = uv ? W_ih[(50 + u) * 3 + c] : 0.f;
    u_n[c] = uv ? W_ih[(100 + u) * 3 + c] : 0.f;
  }
  const float wfc = uv ? W_fc[u] : 0.f;

  // ---- persistent B-fragments (W_hh), bf16x2 split, built once ----
  // tau 0=r,1=z,2=n ; frag f covers k in [32f, 32f+32)
  short8 Bh[3][2], Bl[3][2];
#pragma unroll
  for (int tau = 0; tau < 3; ++tau) {
    const int row = uv ? (tau * 50 + u) : 0;
    const float* Wrow = W_hh + row * HID;
#pragma unroll
    for (int f = 0; f < 2; ++f) {
      union { short a[8]; short8 s; } ph, pl;
#pragma unroll
      for (int e = 0; e < 8; ++e) {
        const int k = 32 * f + 16 * (e >> 2) + 4 * kg + (e & 3);
        const float v = (uv && k < HID) ? Wrow[k] : 0.f;
        __hip_bfloat16 bh = __float2bfloat16(v);
        const float vh = __bfloat162float(bh);
        __hip_bfloat16 bl = __float2bfloat16(v - vh);
        ph.a[e] = *(short*)&bh;
        pl.a[e] = *(short*)&bl;
      }
      Bh[tau][f] = ph.s;
      Bl[tau][f] = pl.s;
    }
  }

  // zero h buf0 (4096 B) — 256 threads x 16 B
  ((float4*)hbuf)[tid] = make_float4(0.f, 0.f, 0.f, 0.f);

  float h[4] = {0.f, 0.f, 0.f, 0.f};          // this lane: unit u, batches 4*kg..4*kg+3

  const int arow = ucol * 128;                 // A-frag row offset (batch = ucol)
  const int axr  = (ucol & 7) << 4;            // A-read XOR
  const floatx4 z4 = {0.f, 0.f, 0.f, 0.f};

  for (int tc = 0; tc < 8; ++tc) {
    // ---- stage x chunk: 16 batches x 64 t x 3 c -> LDS [t][c][m] ----
    {
      const int sm = tid >> 4, seg = tid & 15;
      const float* xb = x + (size_t)(b0 + sm) * (T_LEN * 3) + tc * 192 + seg * 12;
      const float4 v0 = *(const float4*)(xb + 0);
      const float4 v1 = *(const float4*)(xb + 4);
      const float4 v2 = *(const float4*)(xb + 8);
      const float vv[12] = {v0.x, v0.y, v0.z, v0.w, v1.x, v1.y, v1.z, v1.w, v2.x, v2.y, v2.z, v2.w};
#pragma unroll
      for (int jj = 0; jj < 12; ++jj) {
        const int i = seg * 12 + jj;
        *(float*)(xs + (i / 3) * 192 + (i % 3) * 64 + sm * 4) = vv[jj];
      }
    }
    __syncthreads();

#pragma unroll 2
    for (int s = 0; s < 64; ++s) {
      const int par = s & 1;                   // t parity (tc*64 even)
      const char* rp = hbuf + par * 4096;      // read buffer (h(t))
      char*       wp = hbuf + (par ^ 1) * 4096; // write buffer (h(t+1))

      // A-fragments (hi/lo planes)
      const short8 A0h = afrag(rp,        arow, kg, 0, axr);
      const short8 A1h = afrag(rp,        arow, kg, 2, axr);
      const short8 A0l = afrag(rp + 2048, arow, kg, 0, axr);
      const short8 A1l = afrag(rp + 2048, arow, kg, 2, axr);

      // x for this step: batches 4kg..4kg+3, components 0..2
      const float4 xv0 = *(const float4*)(xs + s * 192 + 0 * 64 + kg * 16);
      const float4 xv1 = *(const float4*)(xs + s * 192 + 1 * 64 + kg * 16);
      const float4 xv2 = *(const float4*)(xs + s * 192 + 2 * 64 + kg * 16);

      // MFMA: acc[tau] = h @ W_tau^T  (bf16x2: hh + hl + lh)
      floatx4 acc[3];
#pragma unroll
      for (int tau = 0; tau < 3; ++tau) {
        floatx4 a = __builtin_amdgcn_mfma_f32_16x16x32_bf16(A0h, Bh[tau][0], z4, 0, 0, 0);
        a = __builtin_amdgcn_mfma_f32_16x16x32_bf16(A0h, Bl[tau][0], a, 0, 0, 0);
        a = __builtin_amdgcn_mfma_f32_16x16x32_bf16(A0l, Bh[tau][0], a, 0, 0, 0);
        a = __builtin_amdgcn_mfma_f32_16x16x32_bf16(A1h, Bh[tau][1], a, 0, 0, 0);
        a = __builtin_amdgcn_mfma_f32_16x16x32_bf16(A1h, Bl[tau][1], a, 0, 0, 0);
        a = __builtin_amdgcn_mfma_f32_16x16x32_bf16(A1l, Bh[tau][1], a, 0, 0, 0);
        acc[tau] = a;
      }

      // activations + h update + bf16x2 split + store (batch = 4*kg + r)
      const float xa[4] = {xv0.x, xv0.y, xv0.z, xv0.w};
      const float xb_[4] = {xv1.x, xv1.y, xv1.z, xv1.w};
      const float xc[4] = {xv2.x, xv2.y, xv2.z, xv2.w};
#pragma unroll
      for (int r = 0; r < 4; ++r) {
        const float x0 = xa[r], x1 = xb_[r], x2 = xc[r];
        const float gr = fmaf(x0, u_r[0], fmaf(x1, u_r[1], fmaf(x2, u_r[2], c_r)));
        const float gz = fmaf(x0, u_z[0], fmaf(x1, u_z[1], fmaf(x2, u_z[2], c_z)));
        const float gn = fmaf(x0, u_n[0], fmaf(x1, u_n[1], fmaf(x2, u_n[2], c_ni)));
        const float rr = sigm(acc[0][r] + gr);
        const float zz = sigm(acc[1][r] + gz);
        const float nv = gn + rr * (acc[2][r] + c_nh);
        const float nn = tanh_f(nv);
        const float hn = nn + zz * (h[r] - nn);
        h[r] = hn;
        __hip_bfloat16 bh = __float2bfloat16(hn);
        const float fh = __bfloat162float(bh);
        __hip_bfloat16 bl = __float2bfloat16(hn - fh);
        const int mrow = 4 * kg + r;
        const int off  = mrow * 128 + ((2 * u) ^ ((mrow & 7) << 4));
        *(short*)(wp + off)        = *(short*)&bh;
        *(short*)(wp + 2048 + off) = *(short*)&bl;
      }
      __syncthreads();
    }
  }

  // ---- FC epilogue: out[b] = sum_u h_u * W_fc[u] + b_fc ----
  float p[4];
#pragma unroll
  for (int r = 0; r < 4; ++r) p[r] = h[r] * wfc;
#pragma unroll
  for (int mask = 1; mask < 16; mask <<= 1) {
#pragma unroll
    for (int r = 0; r < 4; ++r) p[r] += __shfl_xor(p[r], mask);
  }
  if (ucol == 0) {
    *(float4*)(lds + (w * 16 + 4 * kg) * 4) = make_float4(p[0], p[1], p[2], p[3]);
  }
  __syncthreads();
  if (tid < 16) {
    float ssum = 0.f;
#pragma unroll
    for (int ww = 0; ww < 4; ++ww) ssum += *(const float*)(lds + (ww * 16 + tid) * 4);
    out[b0 + tid] = ssum + b_fc[0];
  }
}

extern "C" void kernel_launch(void* const* d_in, const int* in_sizes, int n_in,
                              void* d_out, int out_size, void* d_ws, size_t ws_size,
                              hipStream_t stream) {
  const float* x    = (const float*)d_in[0];
  const float* W_ih = (const float*)d_in[1];
  const float* W_hh = (const float*)d_in[2];
  const float* b_ih = (const float*)d_in[3];
  const float* b_hh = (const float*)d_in[4];
  const float* W_fc = (const float*)d_in[5];
  const float* b_fc = (const float*)d_in[6];
  float* out = (float*)d_out;

  dim3 grid(NBATCH / 16);   // 256 blocks, 16 batches each -> 1024 waves = 1/SIMD
  dim3 block(256);          // 4 waves, each owns 16 units' r/z/n tiles
  gru_mfma_kernel<<<grid, block, 0, stream>>>(x, W_ih, W_hh, b_ih, b_hh, W_fc, b_fc, out);
}